// Round 2
// baseline (1290.793 us; speedup 1.0000x reference)
//
#include <hip/hip_runtime.h>
#include <type_traits>

#define N_NODES 100000
#define N_EDGES 1600000
#define NFEAT 512
#define NHID 256
#define NCLASS 40
#define NPAD 100096   // 391 * 256

// bucket sort geometry
#define NBUCK 196     // buckets of 512 rows: (99999>>9)=195 -> 196 buckets
#define BROWS 512
#define NBLK_BIN 256
#define EPB 6250      // 256 * 6250 == 1,600,000 exactly

#define ZOFF (N_NODES * 64)   // dummy zero-row element offset (row 100000)

typedef __bf16 bf16;
typedef __bf16 bf16x8 __attribute__((ext_vector_type(8)));
typedef float f32x4 __attribute__((ext_vector_type(4)));

// ---------------- CSR build via 2-level counting sort ----------------
// Pass 1: per-block LDS histogram over 196 buckets (no global atomics).

__global__ __launch_bounds__(256) void bin_count(const int* __restrict__ rows,
                                                 int* __restrict__ bcnt) {
    __shared__ int hist[NBUCK];
    int t = threadIdx.x, b = blockIdx.x;
    for (int i = t; i < NBUCK; i += 256) hist[i] = 0;
    __syncthreads();
    int base = b * EPB;
    for (int i = t; i < EPB; i += 256) atomicAdd(&hist[rows[base + i] >> 9], 1);
    __syncthreads();
    for (int i = t; i < NBUCK; i += 256) bcnt[i * NBLK_BIN + b] = hist[i];
}

// Pass 2: per-bucket exclusive scan across the 256 blocks -> private segments.
__global__ __launch_bounds__(256) void bin_scan(const int* __restrict__ bcnt,
                                                int* __restrict__ boff2,
                                                int* __restrict__ btot) {
    __shared__ int sh[256];
    int t = threadIdx.x, bu = blockIdx.x;
    int v = bcnt[bu * 256 + t];
    sh[t] = v;
    __syncthreads();
    for (int off = 1; off < 256; off <<= 1) {
        int x = (t >= off) ? sh[t - off] : 0;
        __syncthreads();
        sh[t] += x;
        __syncthreads();
    }
    boff2[t * NBUCK + bu] = sh[t] - v;  // exclusive, [block][bucket] layout
    if (t == 255) btot[bu] = sh[255];
}

// Pass 3: exclusive scan of bucket totals -> bucket base offsets.
__global__ __launch_bounds__(256) void base_scan(const int* __restrict__ btot,
                                                 int* __restrict__ bbase) {
    __shared__ int sh[256];
    int t = threadIdx.x;
    int v = (t < NBUCK) ? btot[t] : 0;
    sh[t] = v;
    __syncthreads();
    for (int off = 1; off < 256; off <<= 1) {
        int x = (t >= off) ? sh[t - off] : 0;
        __syncthreads();
        sh[t] += x;
        __syncthreads();
    }
    if (t < NBUCK) bbase[t] = sh[t] - v;
    if (t == NBUCK - 1) bbase[NBUCK] = sh[t];  // == N_EDGES
}

// Pass 4: scatter packed (rowlocal<<17 | col) into private contiguous segments.
__global__ __launch_bounds__(256) void bin_scatter(const int* __restrict__ rows,
                                                   const int* __restrict__ cols,
                                                   const int* __restrict__ boff2,
                                                   const int* __restrict__ bbase,
                                                   int* __restrict__ binned) {
    __shared__ int cur[NBUCK];
    int t = threadIdx.x, b = blockIdx.x;
    for (int i = t; i < NBUCK; i += 256) cur[i] = bbase[i] + boff2[b * NBUCK + i];
    __syncthreads();
    int base = b * EPB;
    for (int i = t; i < EPB; i += 256) {
        int r = rows[base + i], c = cols[base + i];
        int pos = atomicAdd(&cur[r >> 9], 1);
        binned[pos] = ((r & 511) << 17) | c;  // col < 100000 < 2^17
    }
}

// Pass 5: one block per bucket: per-row counts + prefix in LDS (produces
// rowptr and dinv), then scatter premultiplied col offsets (col*64) into the
// bucket's colidx window.
__global__ __launch_bounds__(256) void bucket_csr(const int* __restrict__ binned,
                                                  const int* __restrict__ bbase,
                                                  int* __restrict__ rowptr,
                                                  int* __restrict__ coff,
                                                  float* __restrict__ dinv) {
    __shared__ int cnt[BROWS];
    __shared__ int pref[BROWS];
    __shared__ int psum[256];
    int t = threadIdx.x, bu = blockIdx.x;
    cnt[t] = 0;
    cnt[t + 256] = 0;
    __syncthreads();
    int base = bbase[bu], end = bbase[bu + 1];
    for (int i = base + t; i < end; i += 256) atomicAdd(&cnt[binned[i] >> 17], 1);
    __syncthreads();
    // exclusive scan of 512 counts (pairwise + Hillis-Steele over 256)
    int c0 = cnt[2 * t], c1 = cnt[2 * t + 1];
    psum[t] = c0 + c1;
    __syncthreads();
    for (int off = 1; off < 256; off <<= 1) {
        int x = (t >= off) ? psum[t - off] : 0;
        __syncthreads();
        psum[t] += x;
        __syncthreads();
    }
    int pex = psum[t] - (c0 + c1);
    pref[2 * t] = pex;
    pref[2 * t + 1] = pex + c0;
    __syncthreads();
#pragma unroll
    for (int j = 0; j < 2; j++) {
        int idx = t + j * 256;
        int grow = bu * BROWS + idx;
        if (grow < N_NODES) {
            rowptr[grow] = base + pref[idx];
            dinv[grow] = 0.5f / (float)(cnt[idx] + 1);  // pre-halved, +1 self-loop
        } else if (grow == N_NODES) {
            rowptr[N_NODES] = N_EDGES;
        }
        pref[idx] += base;  // absolute cursor
    }
    __syncthreads();
    for (int i = base + t; i < end; i += 256) {
        int v = binned[i];
        int pos = atomicAdd(&pref[v >> 17], 1);
        coff[pos] = (v & 0x1FFFF) << 6;  // premultiplied element offset (col*64)
    }
}

// ---------------- weight conversion ----------------

__global__ void cvt_f2b(const float* __restrict__ a, bf16* __restrict__ b, int n) {
    int i = blockIdx.x * 256 + threadIdx.x;
    if (i < n) b[i] = (bf16)a[i];
}

__global__ void pad_w3(const float* __restrict__ W3, const float* __restrict__ b3,
                       bf16* __restrict__ W3p, float* __restrict__ b3p) {
    int i = blockIdx.x * 256 + threadIdx.x;  // over 64*256
    int r = i >> 8;
    W3p[i] = (bf16)((r < NCLASS) ? W3[(size_t)r * 256 + (i & 255)] : 0.f);
    if (i < 64) b3p[i] = (i < NCLASS) ? b3[i] : 0.f;
}

// zero the dummy gather row (index N_NODES) in v0 / v1 / hpad
__global__ void zero_dummy(bf16* v0, bf16* v1, bf16* hp) {
    int i = threadIdx.x;
    if (i < 64) {
        v0[(size_t)ZOFF + i] = (bf16)0.f;
        v1[(size_t)ZOFF + i] = (bf16)0.f;
        hp[(size_t)ZOFF + i] = (bf16)0.f;
    }
}

// ---------------- bf16 MFMA GEMM-NT ----------------
// C[M,Nout] = A[M,K] @ B[Nout,K]^T + bias, A fp32 or bf16 (converted in staging),
// B bf16. OUTMODE 0: bf16 out. OUTMODE 1: dual fp32 [M,40] + bf16 [M,64] padded.

template <int BN, typename AT, bool RELU, int OUTMODE>
__global__ __launch_bounds__(256) void gemm_mfma(const AT* __restrict__ A,
                                                 const bf16* __restrict__ B,
                                                 const float* __restrict__ bias,
                                                 bf16* __restrict__ Cb,
                                                 float* __restrict__ Cf,
                                                 bf16* __restrict__ Cpad,
                                                 int M, int K, int Nout) {
    constexpr int LDT = 56;                      // padded LDS row (bf16), 112 B: 16B-aligned, 2-way banks
    constexpr int WTM = (BN == 128) ? 64 : 32;   // wave tile M
    constexpr int MI = WTM / 16;
    constexpr int WMC = 128 / WTM;               // waves along M
    __shared__ bf16 As[128 * LDT];
    __shared__ bf16 Bs[BN * LDT];

    int tid = threadIdx.x;
    int wave = tid >> 6, lane = tid & 63;
    int waveM = wave % WMC, waveN = wave / WMC;
    int lc = lane & 15, lq = lane >> 4;

    f32x4 acc[MI][4];
#pragma unroll
    for (int i = 0; i < MI; i++)
#pragma unroll
        for (int j = 0; j < 4; j++) acc[i][j] = (f32x4){0.f, 0.f, 0.f, 0.f};

    int sr = tid >> 2;           // staging row base
    int sc = (tid & 3) * 8;      // staging col (8 bf16)

    for (int k0 = 0; k0 < K; k0 += 32) {
        // stage A: 128 x 32
#pragma unroll
        for (int g = 0; g < 2; g++) {
            int r = sr + g * 64;
            int grow = blockIdx.y * 128 + r;
            bf16x8 val = (bf16x8){};
            if (grow < M) {
                if constexpr (std::is_same<AT, float>::value) {
                    const float* ap = A + (size_t)grow * K + k0 + sc;
                    float4 p0 = *(const float4*)ap;
                    float4 p1 = *(const float4*)(ap + 4);
                    val[0] = (bf16)p0.x; val[1] = (bf16)p0.y; val[2] = (bf16)p0.z; val[3] = (bf16)p0.w;
                    val[4] = (bf16)p1.x; val[5] = (bf16)p1.y; val[6] = (bf16)p1.z; val[7] = (bf16)p1.w;
                } else {
                    val = *(const bf16x8*)(A + (size_t)grow * K + k0 + sc);
                }
            }
            *(bf16x8*)&As[r * LDT + sc] = val;
        }
        // stage B: BN x 32 (N dims always exact multiples; no bounds)
#pragma unroll
        for (int g = 0; g < BN / 64; g++) {
            int r = sr + g * 64;
            int brow = blockIdx.x * BN + r;
            *(bf16x8*)&Bs[r * LDT + sc] = *(const bf16x8*)(B + (size_t)brow * K + k0 + sc);
        }
        __syncthreads();

        bf16x8 af[MI], bf[4];
#pragma unroll
        for (int i = 0; i < MI; i++)
            af[i] = *(const bf16x8*)&As[(waveM * WTM + i * 16 + lc) * LDT + lq * 8];
#pragma unroll
        for (int j = 0; j < 4; j++)
            bf[j] = *(const bf16x8*)&Bs[(waveN * 64 + j * 16 + lc) * LDT + lq * 8];
#pragma unroll
        for (int i = 0; i < MI; i++)
#pragma unroll
            for (int j = 0; j < 4; j++)
                acc[i][j] = __builtin_amdgcn_mfma_f32_16x16x32_bf16(af[i], bf[j], acc[i][j], 0, 0, 0);
        __syncthreads();
    }

    // epilogue
#pragma unroll
    for (int i = 0; i < MI; i++) {
        int row0 = blockIdx.y * 128 + waveM * WTM + i * 16 + lq * 4;
#pragma unroll
        for (int j = 0; j < 4; j++) {
            int colL = waveN * 64 + j * 16 + lc;
            int col = blockIdx.x * BN + colL;
            float bv = bias[col];
#pragma unroll
            for (int reg = 0; reg < 4; reg++) {
                int rr = row0 + reg;
                if (rr < M) {
                    float v = acc[i][j][reg] + bv;
                    if (RELU) v = v > 0.f ? v : 0.f;
                    if (OUTMODE == 0) {
                        Cb[(size_t)rr * Nout + col] = (bf16)v;
                    } else {
                        if (col < NCLASS) Cf[(size_t)rr * NCLASS + col] = v;
                        Cpad[(size_t)rr * 64 + col] = (bf16)v;
                    }
                }
            }
        }
    }
}

// ---------------- power-iteration SpMM (bf16 v padded to 64) ----------------
// Edge loop padded to multiple of 8 at read time via dummy zero-row gathers:
// no serial remainder, 8 independent gathers in flight per wave.

__global__ __launch_bounds__(256) void spmm_b(const bf16* __restrict__ v,
                                              const float* __restrict__ h,
                                              const int* __restrict__ rowptr,
                                              const int* __restrict__ coff,
                                              const float* __restrict__ dinv,
                                              bf16* __restrict__ outB,
                                              float* __restrict__ outF,
                                              int final_it) {
    int r = (blockIdx.x * 256 + threadIdx.x) >> 6;  // one wave per row
    int lane = threadIdx.x & 63;
    if (r >= N_NODES || lane >= NCLASS) return;
    int s = rowptr[r], e = rowptr[r + 1];
    float hv = 0.5f * h[(size_t)r * NCLASS + lane];
    float dv = dinv[r];
    float a0 = (float)v[(size_t)r * 64 + lane];  // self-loop
    float a1 = 0.f, a2 = 0.f, a3 = 0.f, a4 = 0.f, a5 = 0.f, a6 = 0.f, a7 = 0.f;
    for (int i = s; i < e; i += 8) {
        int o0 = (i + 0 < e) ? coff[i + 0] : ZOFF;
        int o1 = (i + 1 < e) ? coff[i + 1] : ZOFF;
        int o2 = (i + 2 < e) ? coff[i + 2] : ZOFF;
        int o3 = (i + 3 < e) ? coff[i + 3] : ZOFF;
        int o4 = (i + 4 < e) ? coff[i + 4] : ZOFF;
        int o5 = (i + 5 < e) ? coff[i + 5] : ZOFF;
        int o6 = (i + 6 < e) ? coff[i + 6] : ZOFF;
        int o7 = (i + 7 < e) ? coff[i + 7] : ZOFF;
        a0 += (float)v[(size_t)o0 + lane];
        a1 += (float)v[(size_t)o1 + lane];
        a2 += (float)v[(size_t)o2 + lane];
        a3 += (float)v[(size_t)o3 + lane];
        a4 += (float)v[(size_t)o4 + lane];
        a5 += (float)v[(size_t)o5 + lane];
        a6 += (float)v[(size_t)o6 + lane];
        a7 += (float)v[(size_t)o7 + lane];
    }
    float res = dv * (((a0 + a1) + (a2 + a3)) + ((a4 + a5) + (a6 + a7))) + hv;
    if (final_it) outF[(size_t)r * NCLASS + lane] = res;
    else outB[(size_t)r * 64 + lane] = (bf16)res;
}

// ---------------- launch ----------------

extern "C" void kernel_launch(void* const* d_in, const int* in_sizes, int n_in,
                              void* d_out, int out_size, void* d_ws, size_t ws_size,
                              hipStream_t stream) {
    const float* x  = (const float*)d_in[0];
    const int*   ei = (const int*)d_in[1];
    const float* W1 = (const float*)d_in[2];
    const float* b1 = (const float*)d_in[3];
    const float* W2 = (const float*)d_in[4];
    const float* b2 = (const float*)d_in[5];
    const float* W3 = (const float*)d_in[6];
    const float* b3 = (const float*)d_in[7];
    float* out = (float*)d_out;
    const int* rows = ei;
    const int* cols = ei + N_EDGES;

    // workspace carve (bytes) — ws is ~800 MB, use full-size buffers (no chunking)
    char* p = (char*)d_ws;
    bf16* hid1 = (bf16*)p;                 p += (size_t)N_NODES * NHID * 2;       // 51.2 MB (aliased: binned, then v0)
    bf16* hid2 = (bf16*)p;                 p += (size_t)N_NODES * NHID * 2;       // 51.2 MB (later: v1)
    float* h   = (float*)p;                p += (size_t)N_NODES * NCLASS * 4;     // 16 MB
    bf16* hpad = (bf16*)p;                 p += (size_t)(N_NODES + 1) * 64 * 2;   // 12.8 MB (+dummy row)
    bf16* W1b  = (bf16*)p;                 p += (size_t)NHID * NFEAT * 2;
    bf16* W2b  = (bf16*)p;                 p += (size_t)NHID * NHID * 2;
    bf16* W3p  = (bf16*)p;                 p += (size_t)64 * NHID * 2;
    float* b3p = (float*)p;                p += 64 * 4;
    int* bcnt   = (int*)p;                 p += (size_t)NPAD * 4;                 // uses 196*256 ints
    int* rowptr = (int*)p;                 p += (size_t)(NPAD + 1) * 4;
    int* boff2  = (int*)p;                 p += (size_t)N_NODES * 4;              // uses 256*196 ints
    int* coff   = (int*)p;                 p += (size_t)(N_EDGES + 8) * 4;        // +8 over-read slack
    int* bsum   = (int*)p;                 p += 512 * 4;
    float* dinv = (float*)p;               p += (size_t)N_NODES * 4;

    int* btot  = bsum;          // 196 ints
    int* bbase = bsum + 256;    // 197 ints
    int* binned = (int*)hid1;   // 6.4 MB, dead before MLP starts

    // CSR build: 2-level counting sort, no global atomics, sequential writes
    bin_count<<<NBLK_BIN, 256, 0, stream>>>(rows, bcnt);
    bin_scan<<<NBUCK, 256, 0, stream>>>(bcnt, boff2, btot);
    base_scan<<<1, 256, 0, stream>>>(btot, bbase);
    bin_scatter<<<NBLK_BIN, 256, 0, stream>>>(rows, cols, boff2, bbase, binned);
    bucket_csr<<<NBUCK, 256, 0, stream>>>(binned, bbase, rowptr, coff, dinv);

    // weight conversion
    cvt_f2b<<<(NHID * NFEAT + 255) / 256, 256, 0, stream>>>(W1, W1b, NHID * NFEAT);
    cvt_f2b<<<(NHID * NHID + 255) / 256, 256, 0, stream>>>(W2, W2b, NHID * NHID);
    pad_w3<<<(64 * NHID) / 256, 256, 0, stream>>>(W3, b3, W3p, b3p);

    // MLP, full M in one shot per layer (782 row-blocks -> 3-6 blocks/CU, no tail)
    {
        int M = N_NODES;
        int gy = (M + 127) / 128;
        gemm_mfma<128, float, true, 0><<<dim3(2, gy), 256, 0, stream>>>(
            x, W1b, b1, hid1, nullptr, nullptr, M, NFEAT, NHID);
        gemm_mfma<128, bf16, true, 0><<<dim3(2, gy), 256, 0, stream>>>(
            hid1, W2b, b2, hid2, nullptr, nullptr, M, NHID, NHID);
        gemm_mfma<64, bf16, false, 1><<<dim3(1, gy), 256, 0, stream>>>(
            hid2, W3p, b3p, nullptr, h, hpad, M, NHID, 64);
    }

    // v0/v1 alias hid1/hid2 (dead after MLP); zero the dummy gather row
    bf16* v0 = hid1;
    bf16* v1 = hid2;
    zero_dummy<<<1, 64, 0, stream>>>(v0, v1, hpad);

    // 10 power iterations (v stored bf16, rows padded to 64 = one 128B line)
    const bf16* src = hpad;
    for (int it = 0; it < 10; it++) {
        int fin = (it == 9);
        bf16* dst = (it & 1) ? v1 : v0;
        spmm_b<<<(N_NODES * 64 + 255) / 256, 256, 0, stream>>>(
            src, h, rowptr, coff, dinv, dst, out, fin);
        src = dst;
    }
}

// Round 3
// 1154.438 us; speedup vs baseline: 1.1181x; 1.1181x over previous
//
#include <hip/hip_runtime.h>
#include <type_traits>

#define N_NODES 100000
#define N_EDGES 1600000
#define NFEAT 512
#define NHID 256
#define NCLASS 40
#define NPAD 100096   // 391 * 256

// bucket sort geometry
#define NBUCK 196     // buckets of 512 rows: (99999>>9)=195 -> 196 buckets
#define BROWS 512
#define NBLK_BIN 256
#define EPB 6250      // 256 * 6250 == 1,600,000 exactly

// class-split power iteration: 40 = 32 (pass A) + 8 (pass B)
#define ZA (N_NODES * 32)   // dummy zero-row element offset, pass A
#define ZB (N_NODES * 8)    // dummy zero-row element offset, pass B
#define BLK_A 12500         // 50,000 waves x 2 rows
#define BLK_B 3125          // 12,500 waves x 8 rows

typedef __bf16 bf16;
typedef __bf16 bf16x8 __attribute__((ext_vector_type(8)));
typedef float f32x4 __attribute__((ext_vector_type(4)));

// ---------------- CSR build via 2-level counting sort ----------------

__global__ __launch_bounds__(256) void bin_count(const int* __restrict__ rows,
                                                 int* __restrict__ bcnt) {
    __shared__ int hist[NBUCK];
    int t = threadIdx.x, b = blockIdx.x;
    for (int i = t; i < NBUCK; i += 256) hist[i] = 0;
    __syncthreads();
    int base = b * EPB;
    for (int i = t; i < EPB; i += 256) atomicAdd(&hist[rows[base + i] >> 9], 1);
    __syncthreads();
    for (int i = t; i < NBUCK; i += 256) bcnt[i * NBLK_BIN + b] = hist[i];
}

__global__ __launch_bounds__(256) void bin_scan(const int* __restrict__ bcnt,
                                                int* __restrict__ boff2,
                                                int* __restrict__ btot) {
    __shared__ int sh[256];
    int t = threadIdx.x, bu = blockIdx.x;
    int v = bcnt[bu * 256 + t];
    sh[t] = v;
    __syncthreads();
    for (int off = 1; off < 256; off <<= 1) {
        int x = (t >= off) ? sh[t - off] : 0;
        __syncthreads();
        sh[t] += x;
        __syncthreads();
    }
    boff2[t * NBUCK + bu] = sh[t] - v;  // exclusive, [block][bucket] layout
    if (t == 255) btot[bu] = sh[255];
}

__global__ __launch_bounds__(256) void base_scan(const int* __restrict__ btot,
                                                 int* __restrict__ bbase) {
    __shared__ int sh[256];
    int t = threadIdx.x;
    int v = (t < NBUCK) ? btot[t] : 0;
    sh[t] = v;
    __syncthreads();
    for (int off = 1; off < 256; off <<= 1) {
        int x = (t >= off) ? sh[t - off] : 0;
        __syncthreads();
        sh[t] += x;
        __syncthreads();
    }
    if (t < NBUCK) bbase[t] = sh[t] - v;
    if (t == NBUCK - 1) bbase[NBUCK] = sh[t];  // == N_EDGES
}

__global__ __launch_bounds__(256) void bin_scatter(const int* __restrict__ rows,
                                                   const int* __restrict__ cols,
                                                   const int* __restrict__ boff2,
                                                   const int* __restrict__ bbase,
                                                   int* __restrict__ binned) {
    __shared__ int cur[NBUCK];
    int t = threadIdx.x, b = blockIdx.x;
    for (int i = t; i < NBUCK; i += 256) cur[i] = bbase[i] + boff2[b * NBUCK + i];
    __syncthreads();
    int base = b * EPB;
    for (int i = t; i < EPB; i += 256) {
        int r = rows[base + i], c = cols[base + i];
        int pos = atomicAdd(&cur[r >> 9], 1);
        binned[pos] = ((r & 511) << 17) | c;  // col < 100000 < 2^17
    }
}

__global__ __launch_bounds__(256) void bucket_csr(const int* __restrict__ binned,
                                                  const int* __restrict__ bbase,
                                                  int* __restrict__ rowptr,
                                                  int* __restrict__ colidx,
                                                  float* __restrict__ dinv) {
    __shared__ int cnt[BROWS];
    __shared__ int pref[BROWS];
    __shared__ int psum[256];
    int t = threadIdx.x, bu = blockIdx.x;
    cnt[t] = 0;
    cnt[t + 256] = 0;
    __syncthreads();
    int base = bbase[bu], end = bbase[bu + 1];
    for (int i = base + t; i < end; i += 256) atomicAdd(&cnt[binned[i] >> 17], 1);
    __syncthreads();
    int c0 = cnt[2 * t], c1 = cnt[2 * t + 1];
    psum[t] = c0 + c1;
    __syncthreads();
    for (int off = 1; off < 256; off <<= 1) {
        int x = (t >= off) ? psum[t - off] : 0;
        __syncthreads();
        psum[t] += x;
        __syncthreads();
    }
    int pex = psum[t] - (c0 + c1);
    pref[2 * t] = pex;
    pref[2 * t + 1] = pex + c0;
    __syncthreads();
#pragma unroll
    for (int j = 0; j < 2; j++) {
        int idx = t + j * 256;
        int grow = bu * BROWS + idx;
        if (grow < N_NODES) {
            rowptr[grow] = base + pref[idx];
            dinv[grow] = 0.5f / (float)(cnt[idx] + 1);  // pre-halved, +1 self-loop
        } else if (grow == N_NODES) {
            rowptr[N_NODES] = N_EDGES;
        }
        pref[idx] += base;  // absolute cursor
    }
    __syncthreads();
    for (int i = base + t; i < end; i += 256) {
        int v = binned[i];
        int pos = atomicAdd(&pref[v >> 17], 1);
        colidx[pos] = v & 0x1FFFF;  // raw col
    }
}

// ---------------- weight conversion ----------------

__global__ void cvt_f2b(const float* __restrict__ a, bf16* __restrict__ b, int n) {
    int i = blockIdx.x * 256 + threadIdx.x;
    if (i < n) b[i] = (bf16)a[i];
}

__global__ void pad_w3(const float* __restrict__ W3, const float* __restrict__ b3,
                       bf16* __restrict__ W3p, float* __restrict__ b3p) {
    int i = blockIdx.x * 256 + threadIdx.x;  // over 64*256
    int r = i >> 8;
    W3p[i] = (bf16)((r < NCLASS) ? W3[(size_t)r * 256 + (i & 255)] : 0.f);
    if (i < 64) b3p[i] = (i < NCLASS) ? b3[i] : 0.f;
}

// zero the dummy gather rows (index N_NODES) in all v buffers
__global__ void zero_dummy(bf16* vAi, bf16* vA0, bf16* vA1,
                           bf16* vBi, bf16* vB0, bf16* vB1) {
    int i = threadIdx.x;
    if (i < 32) {
        vAi[(size_t)ZA + i] = (bf16)0.f;
        vA0[(size_t)ZA + i] = (bf16)0.f;
        vA1[(size_t)ZA + i] = (bf16)0.f;
    }
    if (i < 8) {
        vBi[(size_t)ZB + i] = (bf16)0.f;
        vB0[(size_t)ZB + i] = (bf16)0.f;
        vB1[(size_t)ZB + i] = (bf16)0.f;
    }
}

// ---------------- bf16 MFMA GEMM-NT, 2-phase double-buffered ----------------
// C[M,Nout] = A[M,K] @ B[Nout,K]^T + bias. A fp32 or bf16 (converted in staging).
// OUTMODE 0: bf16 out. OUTMODE 1: split outputs hA/hB (fp32, pre-halved) +
// vA0/vB0 (bf16 initial power-iteration state).

template <int BN, typename AT, bool RELU, int OUTMODE>
__global__ __launch_bounds__(256) void gemm_mfma(const AT* __restrict__ A,
                                                 const bf16* __restrict__ B,
                                                 const float* __restrict__ bias,
                                                 bf16* __restrict__ Cb,
                                                 float* __restrict__ hA,
                                                 float* __restrict__ hB,
                                                 bf16* __restrict__ vA0,
                                                 bf16* __restrict__ vB0,
                                                 int M, int K, int Nout) {
    constexpr int LDT = 40;                      // 80 B rows: 16B-aligned, 2-way banks on b128 reads
    constexpr int WTM = (BN == 128) ? 64 : 32;   // wave tile M
    constexpr int MI = WTM / 16;
    constexpr int WMC = 128 / WTM;               // waves along M
    constexpr int BG = BN / 64;
    constexpr bool AF32 = std::is_same<AT, float>::value;
    __shared__ bf16 As[2][128 * LDT];
    __shared__ bf16 Bs[2][BN * LDT];

    int tid = threadIdx.x;
    int wave = tid >> 6, lane = tid & 63;
    int waveM = wave % WMC, waveN = wave / WMC;
    int lc = lane & 15, lq = lane >> 4;

    f32x4 acc[MI][4];
#pragma unroll
    for (int i = 0; i < MI; i++)
#pragma unroll
        for (int j = 0; j < 4; j++) acc[i][j] = (f32x4){0.f, 0.f, 0.f, 0.f};

    int sr = tid >> 2;           // staging row base (0..63)
    int sc = (tid & 3) * 8;      // staging col (8 bf16)

    // staging registers (issue-early / write-late)
    float4 pa[2][2];
    bf16x8 ba[2];
    bf16x8 bb[BG];

    auto LOAD = [&](int k0) {
#pragma unroll
        for (int g = 0; g < 2; g++) {
            int grow = blockIdx.y * 128 + sr + g * 64;
            if constexpr (AF32) {
                if (grow < M) {
                    const float* ap = A + (size_t)grow * K + k0 + sc;
                    pa[g][0] = *(const float4*)ap;
                    pa[g][1] = *(const float4*)(ap + 4);
                } else {
                    pa[g][0] = (float4){0.f, 0.f, 0.f, 0.f};
                    pa[g][1] = (float4){0.f, 0.f, 0.f, 0.f};
                }
            } else {
                ba[g] = (grow < M) ? *(const bf16x8*)(A + (size_t)grow * K + k0 + sc)
                                   : (bf16x8){};
            }
        }
#pragma unroll
        for (int g = 0; g < BG; g++) {
            int brow = blockIdx.x * BN + sr + g * 64;
            bb[g] = *(const bf16x8*)(B + (size_t)brow * K + k0 + sc);
        }
    };
    auto STORE = [&](int buf) {
#pragma unroll
        for (int g = 0; g < 2; g++) {
            bf16x8 val;
            if constexpr (AF32) {
                val[0] = (bf16)pa[g][0].x; val[1] = (bf16)pa[g][0].y;
                val[2] = (bf16)pa[g][0].z; val[3] = (bf16)pa[g][0].w;
                val[4] = (bf16)pa[g][1].x; val[5] = (bf16)pa[g][1].y;
                val[6] = (bf16)pa[g][1].z; val[7] = (bf16)pa[g][1].w;
            } else {
                val = ba[g];
            }
            *(bf16x8*)&As[buf][(sr + g * 64) * LDT + sc] = val;
        }
#pragma unroll
        for (int g = 0; g < BG; g++)
            *(bf16x8*)&Bs[buf][(sr + g * 64) * LDT + sc] = bb[g];
    };

    int nt = K / 32;
    LOAD(0);
    STORE(0);
    __syncthreads();
    int cur = 0;
    for (int t = 0; t < nt; t++) {
        if (t + 1 < nt) LOAD((t + 1) * 32);   // issue next-tile loads early
        bf16x8 af[MI], bfr[4];
#pragma unroll
        for (int i = 0; i < MI; i++)
            af[i] = *(const bf16x8*)&As[cur][(waveM * WTM + i * 16 + lc) * LDT + lq * 8];
#pragma unroll
        for (int j = 0; j < 4; j++)
            bfr[j] = *(const bf16x8*)&Bs[cur][(waveN * 64 + j * 16 + lc) * LDT + lq * 8];
#pragma unroll
        for (int i = 0; i < MI; i++)
#pragma unroll
            for (int j = 0; j < 4; j++)
                acc[i][j] = __builtin_amdgcn_mfma_f32_16x16x32_bf16(af[i], bfr[j], acc[i][j], 0, 0, 0);
        if (t + 1 < nt) STORE(cur ^ 1);       // vmcnt wait lands here, after MFMAs
        __syncthreads();                      // one barrier per K-step
        cur ^= 1;
    }

    // epilogue
#pragma unroll
    for (int i = 0; i < MI; i++) {
        int row0 = blockIdx.y * 128 + waveM * WTM + i * 16 + lq * 4;
#pragma unroll
        for (int j = 0; j < 4; j++) {
            int colL = waveN * 64 + j * 16 + lc;
            int col = blockIdx.x * BN + colL;
            float bv = bias[col];
#pragma unroll
            for (int reg = 0; reg < 4; reg++) {
                int rr = row0 + reg;
                if (rr < M) {
                    float v = acc[i][j][reg] + bv;
                    if (RELU) v = v > 0.f ? v : 0.f;
                    if (OUTMODE == 0) {
                        Cb[(size_t)rr * Nout + col] = (bf16)v;
                    } else {
                        if (col < 32) {
                            hA[(size_t)rr * 32 + col] = 0.5f * v;
                            vA0[(size_t)rr * 32 + col] = (bf16)v;
                        } else if (col < NCLASS) {
                            hB[(size_t)rr * 8 + (col - 32)] = 0.5f * v;
                            vB0[(size_t)rr * 8 + (col - 32)] = (bf16)v;
                        }
                    }
                }
            }
        }
    }
}

// ---------------- class-split power-iteration SpMM ----------------
// Pass A (blocks 0..BLK_A-1): 32 classes, 64 B rows, 2 rows per wave.
// Pass B (blocks BLK_A..):    8 classes, 16 B rows (1.6 MB, L2-resident),
//                             8 rows per wave.

__global__ __launch_bounds__(256) void spmm_split(const bf16* __restrict__ vA,
                                                  const bf16* __restrict__ vB,
                                                  const float* __restrict__ hA,
                                                  const float* __restrict__ hB,
                                                  const int* __restrict__ rowptr,
                                                  const int* __restrict__ colidx,
                                                  const float* __restrict__ dinv,
                                                  bf16* __restrict__ oA,
                                                  bf16* __restrict__ oB,
                                                  float* __restrict__ outF,
                                                  int final_it) {
    int b = blockIdx.x;
    int lane = threadIdx.x & 63;
    if (b < BLK_A) {
        int w = b * 4 + (threadIdx.x >> 6);   // 0..49999
        int cls = lane & 31;
        int r = 2 * w + (lane >> 5);
        int s = rowptr[r], e = rowptr[r + 1];
        int d = e - s;
        int od = __shfl_xor(d, 32);
        int dmax = d > od ? d : od;
        float hv = hA[(size_t)r * 32 + cls];  // pre-halved
        float dv = dinv[r];
        float a0 = (float)vA[(size_t)r * 32 + cls];  // self-loop
        float a1 = 0.f, a2 = 0.f, a3 = 0.f, a4 = 0.f, a5 = 0.f, a6 = 0.f, a7 = 0.f;
        for (int i = 0; i < dmax; i += 8) {
#define GA(J, ACC)                                                      \
            {                                                           \
                int off = (i + J < d) ? (colidx[s + i + J] << 5) : ZA;  \
                ACC += (float)vA[(size_t)off + cls];                    \
            }
            GA(0, a0) GA(1, a1) GA(2, a2) GA(3, a3)
            GA(4, a4) GA(5, a5) GA(6, a6) GA(7, a7)
#undef GA
        }
        float res = dv * (((a0 + a1) + (a2 + a3)) + ((a4 + a5) + (a6 + a7))) + hv;
        if (final_it) outF[(size_t)r * NCLASS + cls] = res;
        else oA[(size_t)r * 32 + cls] = (bf16)res;
    } else {
        int w = (b - BLK_A) * 4 + (threadIdx.x >> 6);  // 0..12499
        int cls = lane & 7;
        int r = 8 * w + (lane >> 3);
        int s = rowptr[r], e = rowptr[r + 1];
        int d = e - s;
        int m = d;
        int x = __shfl_xor(m, 8);  m = m > x ? m : x;
        x = __shfl_xor(m, 16);     m = m > x ? m : x;
        x = __shfl_xor(m, 32);     m = m > x ? m : x;
        float hv = hB[(size_t)r * 8 + cls];   // pre-halved
        float dv = dinv[r];
        float a0 = (float)vB[(size_t)r * 8 + cls];  // self-loop
        float a1 = 0.f, a2 = 0.f, a3 = 0.f, a4 = 0.f, a5 = 0.f, a6 = 0.f, a7 = 0.f;
        for (int i = 0; i < m; i += 8) {
#define GB(J, ACC)                                                      \
            {                                                           \
                int off = (i + J < d) ? (colidx[s + i + J] << 3) : ZB;  \
                ACC += (float)vB[(size_t)off + cls];                    \
            }
            GB(0, a0) GB(1, a1) GB(2, a2) GB(3, a3)
            GB(4, a4) GB(5, a5) GB(6, a6) GB(7, a7)
#undef GB
        }
        float res = dv * (((a0 + a1) + (a2 + a3)) + ((a4 + a5) + (a6 + a7))) + hv;
        if (final_it) outF[(size_t)r * NCLASS + 32 + cls] = res;
        else oB[(size_t)r * 8 + cls] = (bf16)res;
    }
}

// ---------------- launch ----------------

extern "C" void kernel_launch(void* const* d_in, const int* in_sizes, int n_in,
                              void* d_out, int out_size, void* d_ws, size_t ws_size,
                              hipStream_t stream) {
    const float* x  = (const float*)d_in[0];
    const int*   ei = (const int*)d_in[1];
    const float* W1 = (const float*)d_in[2];
    const float* b1 = (const float*)d_in[3];
    const float* W2 = (const float*)d_in[4];
    const float* b2 = (const float*)d_in[5];
    const float* W3 = (const float*)d_in[6];
    const float* b3 = (const float*)d_in[7];
    float* out = (float*)d_out;
    const int* rows = ei;
    const int* cols = ei + N_EDGES;

    // workspace carve (bytes)
    char* p = (char*)d_ws;
    bf16* hid1 = (bf16*)p;                 p += (size_t)N_NODES * NHID * 2;       // 51.2 MB (aliased: binned)
    bf16* hid2 = (bf16*)p;                 p += (size_t)N_NODES * NHID * 2;       // 51.2 MB
    float* hA  = (float*)p;                p += (size_t)N_NODES * 32 * 4;         // 12.8 MB
    float* hB  = (float*)p;                p += (size_t)N_NODES * 8 * 4;          // 3.2 MB
    bf16* vAi  = (bf16*)p;                 p += (size_t)(N_NODES + 1) * 32 * 2;   // 6.4 MB
    bf16* vA0  = (bf16*)p;                 p += (size_t)(N_NODES + 1) * 32 * 2;
    bf16* vA1  = (bf16*)p;                 p += (size_t)(N_NODES + 1) * 32 * 2;
    bf16* vBi  = (bf16*)p;                 p += (size_t)(N_NODES + 1) * 8 * 2;    // 1.6 MB
    bf16* vB0  = (bf16*)p;                 p += (size_t)(N_NODES + 1) * 8 * 2;
    bf16* vB1  = (bf16*)p;                 p += (size_t)(N_NODES + 1) * 8 * 2;
    bf16* W1b  = (bf16*)p;                 p += (size_t)NHID * NFEAT * 2;
    bf16* W2b  = (bf16*)p;                 p += (size_t)NHID * NHID * 2;
    bf16* W3p  = (bf16*)p;                 p += (size_t)64 * NHID * 2;
    float* b3p = (float*)p;                p += 64 * 4;
    int* bcnt   = (int*)p;                 p += (size_t)NPAD * 4;
    int* rowptr = (int*)p;                 p += (size_t)(NPAD + 1) * 4;
    int* boff2  = (int*)p;                 p += (size_t)N_NODES * 4;
    int* colidx = (int*)p;                 p += (size_t)(N_EDGES + 64) * 4;       // +64 over-read slack
    int* bsum   = (int*)p;                 p += 512 * 4;
    float* dinv = (float*)p;               p += (size_t)N_NODES * 4;

    int* btot  = bsum;          // 196 ints
    int* bbase = bsum + 256;    // 197 ints
    int* binned = (int*)hid1;   // 6.4 MB, dead before MLP starts

    // CSR build
    bin_count<<<NBLK_BIN, 256, 0, stream>>>(rows, bcnt);
    bin_scan<<<NBUCK, 256, 0, stream>>>(bcnt, boff2, btot);
    base_scan<<<1, 256, 0, stream>>>(btot, bbase);
    bin_scatter<<<NBLK_BIN, 256, 0, stream>>>(rows, cols, boff2, bbase, binned);
    bucket_csr<<<NBUCK, 256, 0, stream>>>(binned, bbase, rowptr, colidx, dinv);

    // weight conversion
    cvt_f2b<<<(NHID * NFEAT + 255) / 256, 256, 0, stream>>>(W1, W1b, NHID * NFEAT);
    cvt_f2b<<<(NHID * NHID + 255) / 256, 256, 0, stream>>>(W2, W2b, NHID * NHID);
    pad_w3<<<(64 * NHID) / 256, 256, 0, stream>>>(W3, b3, W3p, b3p);

    // MLP, full M per layer
    {
        int M = N_NODES;
        int gy = (M + 127) / 128;
        gemm_mfma<128, float, true, 0><<<dim3(2, gy), 256, 0, stream>>>(
            x, W1b, b1, hid1, nullptr, nullptr, nullptr, nullptr, M, NFEAT, NHID);
        gemm_mfma<128, bf16, true, 0><<<dim3(2, gy), 256, 0, stream>>>(
            hid1, W2b, b2, hid2, nullptr, nullptr, nullptr, nullptr, M, NHID, NHID);
        gemm_mfma<64, bf16, false, 1><<<dim3(1, gy), 256, 0, stream>>>(
            hid2, W3p, b3p, nullptr, hA, hB, vAi, vBi, M, NHID, 64);
    }

    zero_dummy<<<1, 64, 0, stream>>>(vAi, vA0, vA1, vBi, vB0, vB1);

    // 10 power iterations, class-split (A: 32 classes, B: 8 classes), fused launch
    const bf16* sA = vAi;
    const bf16* sB = vBi;
    for (int it = 0; it < 10; it++) {
        int fin = (it == 9);
        bf16* dA = (it & 1) ? vA1 : vA0;
        bf16* dB = (it & 1) ? vB1 : vB0;
        spmm_split<<<BLK_A + BLK_B, 256, 0, stream>>>(
            sA, sB, hA, hB, rowptr, colidx, dinv, dA, dB, out, fin);
        sA = dA;
        sB = dB;
    }
}